// Round 3
// baseline (246.451 us; speedup 1.0000x reference)
//
#include <hip/hip_runtime.h>
#include <stdint.h>

#define NM 16
#define HW_P 589824            // 768*768 pixels per mask
#define U8PM 9216              // u64 words per mask
#define SLC 2304               // u64 words per slice (U8PM/4)
#define F4PM 147456            // float4s per mask
#define F4PT 2359296           // float4s per tensor
#define PT 256                 // threads per pipeline WG (4 waves)
#define NG 8                   // pipeline stages (2 columns each)
#define NS 4                   // slice-WGs per stage
#define NWIN 32                // winner WGs (NG*NS)
#define EWG 256                // election WGs (256/8 XCDs: pigeonhole -> one XCD gets 32)

typedef unsigned long long u64;
typedef float vf4 __attribute__((ext_vector_type(4)));

// meta layout (u32 words; 32 KB zeroed by binarize block 0):
//   [0..7]    cnt[xcc]
//   [8]       winner
//   [16..31]  flagsA
//   [32..47]  flagsB
//   [64  + g*16]                acc0[g] (u64): b-col popcount init reduce
//   [192 + g*16 + s*4 + w]      ackF: consumer wave's last consumed row+1
//   [320 + ((g*16+t)*16)+s*4+w] prodF: bit0 valid | bits1..20 pca | bit21 fa
//   [2112+ (g*16+t)*16]         accA (u64): cnt<<48 | I1<<24 | I0
//                +2 words       accB (u64): cnt<<48 | PC<<24 | T
//
// DECOMPOSITION: each stage = 4 slice-WGs x 256 thr; slice s owns u64 words
// [s*2304, (s+1)*2304) of every mask. Per-step per-CU data volume drops 4x
// (18KB load + 18KB store vs 73KB+73KB) -- the dominant chain terms of the
// previous 8-WG design. Cross-WG reduce: WG-local LDS reduce -> one packed
// u64 atomicAdd per WG into a UNIQUE pre-zeroed per-(g,t) accumulator ->
// all waves poll until count==4. Decisions are replicated bit-identically in
// every WG (same int sums -> same fp32 ops), so pca/pcb/fb state stays
// consistent without broadcast.
//
// Handoff per (boundary, slice, wave) channel: identical tid->address maps,
// 2 L2-resident slots (t&1) gated by per-wave acks, consumer loads sc0
// (L1-bypass), producer stores plain (write-through), flag strictly after
// wave-local vmcnt(0).

__device__ __forceinline__ unsigned aload(const unsigned* p) {
    return __hip_atomic_load(p, __ATOMIC_RELAXED, __HIP_MEMORY_SCOPE_AGENT);
}
__device__ __forceinline__ void astore(unsigned* p, unsigned v) {
    __hip_atomic_store(p, v, __ATOMIC_RELAXED, __HIP_MEMORY_SCOPE_AGENT);
}
__device__ __forceinline__ unsigned afadd(unsigned* p, unsigned v) {
    return __hip_atomic_fetch_add(p, v, __ATOMIC_RELAXED, __HIP_MEMORY_SCOPE_AGENT);
}
__device__ __forceinline__ u64 aload64(const u64* p) {
    return __hip_atomic_load(p, __ATOMIC_RELAXED, __HIP_MEMORY_SCOPE_AGENT);
}
__device__ __forceinline__ void afadd64(u64* p, u64 v) {
    (void)__hip_atomic_fetch_add(p, v, __ATOMIC_RELAXED, __HIP_MEMORY_SCOPE_AGENT);
}

#define LOAD8_SC0(dst, addr) \
    asm volatile("global_load_dwordx2 %0, %1, off sc0" : "=v"(dst) : "v"(addr))

__device__ __forceinline__ uint32_t spread4(uint32_t x) {
    uint32_t t = (x | (x << 12)) & 0x000F000Fu;
    t = (t | (t << 6)) & 0x03030303u;
    t = (t | (t << 3)) & 0x11111111u;
    return t;
}

// ---------------- kernel 1: binarize (coalesced) + meta zero ---------------
__global__ __launch_bounds__(256) void binarize_kernel(
    const float* __restrict__ ma, const float* __restrict__ mb,
    uint32_t* __restrict__ bitsA, uint32_t* __restrict__ bitsB,
    uint4* __restrict__ meta4)
{
    if (blockIdx.x == 0) {          // zero 32 KB of control state (ws is 0xAA)
        uint4 z; z.x = z.y = z.z = z.w = 0u;
#pragma unroll
        for (int i = 0; i < 8; ++i)
            meta4[threadIdx.x + 256 * i] = z;
    }
    int g = blockIdx.x * 256 + threadIdx.x;        // float4 index
    int tensor = (g >= F4PT);                      // %64==0: wave-uniform
    int lg = tensor ? (g - F4PT) : g;
    const float* src = tensor ? mb : ma;
    vf4 v = __builtin_nontemporal_load(((const vf4*)src) + lg);
    u64 q0 = __ballot(v.x > 0.0f);
    u64 q1 = __ballot(v.y > 0.0f);
    u64 q2 = __ballot(v.z > 0.0f);
    u64 q3 = __ballot(v.w > 0.0f);
    int lane = threadIdx.x & 63;
    if (lane < 8) {
        uint32_t wd = spread4((uint32_t)(q0 >> (8 * lane)) & 0xFFu)
                    | (spread4((uint32_t)(q1 >> (8 * lane)) & 0xFFu) << 1)
                    | (spread4((uint32_t)(q2 >> (8 * lane)) & 0xFFu) << 2)
                    | (spread4((uint32_t)(q3 >> (8 * lane)) & 0xFFu) << 3);
        uint32_t* bits = tensor ? bitsB : bitsA;
        bits[((lg & ~63) >> 3) + lane] = wd;       // word = 8 float4s
    }
}

// -------- kernel 2: same-XCD pipeline, 8 stages x 4 slice-WGs --------------
__global__ __launch_bounds__(PT, 1) void pipeline_kernel(
    const float* __restrict__ sa, const float* __restrict__ sb,
    uint32_t* bitsA, uint32_t* bitsB, unsigned* meta, u64* msg)
{
    unsigned* cnt    = meta;
    unsigned* winner = meta + 8;
    int* flagsA      = (int*)(meta + 16);
    int* flagsB      = (int*)(meta + 32);

    const int tid = threadIdx.x;
    const int wave = tid >> 6, lane = tid & 63;

    __shared__ int s_gs;
    __shared__ int4 part[2][4];

    // ---- election (tid0): first XCD to collect 32 reporters wins ----
    if (tid == 0) {
        int xcc;
        asm volatile("s_getreg_b32 %0, hwreg(HW_REG_XCC_ID)" : "=s"(xcc));
        xcc &= 7;
        unsigned slot = afadd(&cnt[xcc], 1u);
        int mine = -1;
        if (slot < NWIN) {
            if (slot == NWIN - 1) {   // 32nd reporter of this XCD claims the win
                unsigned exp = 0u;
                __hip_atomic_compare_exchange_strong(
                    winner, &exp, (unsigned)(xcc + 1),
                    __ATOMIC_RELAXED, __ATOMIC_RELAXED, __HIP_MEMORY_SCOPE_AGENT);
            }
            unsigned w;
            while (!(w = aload(winner))) __builtin_amdgcn_s_sleep(1);
            if (w == (unsigned)(xcc + 1)) mine = (int)slot;
        }
        s_gs = mine;
    }
    __syncthreads();
    const int gs = s_gs;
    if (gs < 0) return;             // 224 losers exit — zero interference
    const int g = gs >> 2, s = gs & 3;

    const int c0 = 2 * g, c1 = 2 * g + 1;
    const u64* A64 = (const u64*)bitsA;
    u64* B64 = (u64*)bitsB;
    const int soff = s * SLC + tid;                 // slice-local u64 offset
    unsigned* ackO = meta + 192 + g * 16 + s * 4 + wave;         // g < NG-1
    unsigned* ackI = meta + 192 + (g - 1) * 16 + s * 4 + wave;   // g > 0

    u64 b0[9], b1[9];

    // ---- load b-column slices + init popcount reduce across 4 WGs ----
    int v0 = 0, v1 = 0;
#pragma unroll
    for (int k = 0; k < 9; ++k) {
        b0[k] = B64[(size_t)c0 * U8PM + soff + 256 * k];
        b1[k] = B64[(size_t)c1 * U8PM + soff + 256 * k];
        v0 += __popcll(b0[k]); v1 += __popcll(b1[k]);
    }
#pragma unroll
    for (int off = 32; off >= 1; off >>= 1) {
        v0 += __shfl_xor(v0, off); v1 += __shfl_xor(v1, off);
    }
    if (lane == 0) { int4 p; p.x = v0; p.y = v1; p.z = 0; p.w = 0; part[0][wave] = p; }
    __syncthreads();
    int wv0 = 0, wv1 = 0;
#pragma unroll
    for (int w = 0; w < 4; ++w) { wv0 += part[0][w].x; wv1 += part[0][w].y; }
    u64* a0p = (u64*)(meta + 64 + g * 16);
    if (tid == 0)
        afadd64(a0p, (1ull << 48) | ((u64)wv1 << 24) | (u64)wv0);
    u64 iv;
    do { iv = aload64(a0p); } while ((iv >> 48) != NS);
    int pcb0 = (int)(iv & 0xFFFFFFu);
    int pcb1 = (int)((iv >> 24) & 0xFFFFFFu);
    float sb0 = sb[c0], sb1 = sb[c1];
    int fb0 = 0, fb1 = 0;
    __syncthreads();   // part[0] free for t=0 writes

    for (int t = 0; t < NM; ++t) {
        int pca, fa;
        u64 a[9];

        // ---- obtain row-t slice (per-wave channel) ----
        if (g == 0) {
            pca = 0; fa = 0;
#pragma unroll
            for (int k = 0; k < 9; ++k)
                a[k] = A64[(size_t)t * U8PM + soff + 256 * k];
        } else {
            const unsigned* fptr = meta + 320 + ((g - 1) * 16 + t) * 16 + s * 4 + wave;
            unsigned v;
            do { v = aload(fptr); } while (!v);
            asm volatile("" ::: "memory");   // pin data loads below the poll
            pca = (int)((v >> 1) & 0xFFFFFu);
            fa  = (int)((v >> 21) & 1u);
            const u64* srcp = msg + (size_t)((g - 1) * 2 + (t & 1)) * U8PM + soff;
#pragma unroll
            for (int k = 0; k < 9; ++k)
                LOAD8_SC0(a[k], srcp + 256 * k);    // 8B, L1-bypass
            asm volatile("s_waitcnt vmcnt(0)" ::: "memory");
            __builtin_amdgcn_sched_barrier(0);
            if (lane == 0) astore(ackI, (unsigned)(t + 1));  // slot consumed
        }

        // ---- fused popc terms ----
        int i0 = 0, i1 = 0, itr = 0, ipc = 0;
#pragma unroll
        for (int k = 0; k < 9; ++k) {
            u64 ab0 = a[k] & b0[k];
            i0 += __popcll(ab0);
            i1 += __popcll(a[k] & b1[k]);
            itr += __popcll(ab0 & b1[k]);
        }
        if (g == 0) {
#pragma unroll
            for (int k = 0; k < 9; ++k) ipc += __popcll(a[k]);
        }
#pragma unroll
        for (int off = 32; off >= 1; off >>= 1) {
            i0 += __shfl_xor(i0, off); i1 += __shfl_xor(i1, off);
            itr += __shfl_xor(itr, off); ipc += __shfl_xor(ipc, off);
        }
        if (lane == 0) {
            int4 p; p.x = i0; p.y = i1; p.z = itr; p.w = ipc;
            part[t & 1][wave] = p;
        }
        __syncthreads();   // single per-step barrier (parity-dbuf part[])
        int I0 = 0, I1 = 0, T = 0, PC = 0;
#pragma unroll
        for (int w = 0; w < 4; ++w) {
            int4 p = part[t & 1][w];
            I0 += p.x; I1 += p.y; T += p.z; PC += p.w;
        }

        // ---- cross-WG reduce: one packed atomic per WG, poll count==4 ----
        u64* accA = (u64*)(meta + 2112 + (g * 16 + t) * 16);
        u64* accB = accA + 1;
        if (tid == 0) {
            afadd64(accB, (1ull << 48) | ((u64)PC << 24) | (u64)T);
            afadd64(accA, (1ull << 48) | ((u64)I1 << 24) | (u64)I0);
        }
        u64 va, vb;
        do { va = aload64(accA); } while ((va >> 48) != NS);
        do { vb = aload64(accB); } while ((vb >> 48) != NS);
        I0 = (int)(va & 0xFFFFFFu); I1 = (int)((va >> 24) & 0xFFFFFFu);
        T  = (int)(vb & 0xFFFFFFu); PC = (int)((vb >> 24) & 0xFFFFFFu);
        if (g == 0) pca = PC;

        float sai = sa[t];
        // ---- pair (t,c0): replicate reference fp32 arithmetic exactly ----
        bool aupd = false;
        {
            int inter = I0;
            int uni = pca + pcb0 - inter;
            float iou = (float)inter / fmaxf((float)uni, 1.0f);
            bool aw = sai > sb0;
            if (iou > 0.8f) { if (aw) fb0 = 1; else fa = 1; }
            else if (inter > 0) {
                if (aw) {
                    pcb0 -= inter;
#pragma unroll
                    for (int k = 0; k < 9; ++k) b0[k] &= ~a[k];
                } else {
                    pca -= inter; aupd = true;
#pragma unroll
                    for (int k = 0; k < 9; ++k) a[k] &= ~b0[k];
                }
            }
        }
        // ---- pair (t,c1): exact inter via speculative triple term ----
        {
            int inter = aupd ? (I1 - T) : I1;
            int uni = pca + pcb1 - inter;
            float iou = (float)inter / fmaxf((float)uni, 1.0f);
            bool aw = sai > sb1;
            if (iou > 0.8f) { if (aw) fb1 = 1; else fa = 1; }
            else if (inter > 0) {
                if (aw) {
                    pcb1 -= inter;
#pragma unroll
                    for (int k = 0; k < 9; ++k) b1[k] &= ~a[k];
                } else {
                    pca -= inter;
#pragma unroll
                    for (int k = 0; k < 9; ++k) a[k] &= ~b1[k];
                }
            }
        }

        // ---- forward / finalize row slice (per-wave channel) ----
        if (g < NG - 1) {
            if (t >= 2) {                       // slot t&1 reusable? (rare spin)
                while ((int)aload(ackO) < t - 1) {}
            }
            asm volatile("" ::: "memory");      // pin stores below the ack check
            u64* dst = msg + (size_t)(g * 2 + (t & 1)) * U8PM + soff;
#pragma unroll
            for (int k = 0; k < 9; ++k)
                dst[256 * k] = a[k];            // plain: write-through into L2
            asm volatile("s_waitcnt vmcnt(0)" ::: "memory");  // wave-local drain
            if (lane == 0)                      // own flag strictly after data
                astore(meta + 320 + (g * 16 + t) * 16 + s * 4 + wave,
                       1u | ((unsigned)pca << 1) | ((unsigned)fa << 21));
        } else {
            u64* dst = (u64*)bitsA + (size_t)t * U8PM + soff;
#pragma unroll
            for (int k = 0; k < 9; ++k)
                dst[256 * k] = a[k];
            if (s == 0 && tid == 0) flagsA[t] = fa;
        }
    }

    // final b-column slices + flags; dispatch-end flush publishes to expand
#pragma unroll
    for (int k = 0; k < 9; ++k) {
        B64[(size_t)c0 * U8PM + soff + 256 * k] = b0[k];
        B64[(size_t)c1 * U8PM + soff + 256 * k] = b1[k];
    }
    if (s == 0 && tid == 0) { flagsB[c0] = fb0; flagsB[c1] = fb1; }
}

// ---------------- kernel 3: expand (coalesced, NT stores) ------------------
__global__ __launch_bounds__(256) void expand_kernel(
    const uint32_t* __restrict__ bitsA, const uint32_t* __restrict__ bitsB,
    const int* __restrict__ meta, float* __restrict__ out)
{
    int g = blockIdx.x * 256 + threadIdx.x;        // float4 index
    int tensor = (g >= F4PT);
    int lg = tensor ? (g - F4PT) : g;
    const uint32_t* bits = tensor ? bitsB : bitsA;
    const int* flags = meta + (tensor ? 32 : 16);
    int m = lg / F4PM;
    bool keep = (flags[m] == 0);
    uint32_t wd = keep ? bits[lg >> 3] : 0u;
    int sh = (lg & 7) * 4;
    vf4 o;
    o.x = ((wd >> (sh + 0)) & 1u) ? 1.0f : 0.0f;
    o.y = ((wd >> (sh + 1)) & 1u) ? 1.0f : 0.0f;
    o.z = ((wd >> (sh + 2)) & 1u) ? 1.0f : 0.0f;
    o.w = ((wd >> (sh + 3)) & 1u) ? 1.0f : 0.0f;
    __builtin_nontemporal_store(o, ((vf4*)out) + g);
    if (g < 2 * NM) {   // keep_a / keep_b tail (flagsA,flagsB contiguous)
        out[(size_t)2 * NM * HW_P + g] = meta[16 + g] ? 0.0f : 1.0f;
    }
}

extern "C" void kernel_launch(void* const* d_in, const int* in_sizes, int n_in,
                              void* d_out, int out_size, void* d_ws, size_t ws_size,
                              hipStream_t stream)
{
    const float* ma = (const float*)d_in[0];
    const float* mb = (const float*)d_in[1];
    const float* sa = (const float*)d_in[2];
    const float* sb = (const float*)d_in[3];
    float* out = (float*)d_out;
    char* ws = (char*)d_ws;

    uint32_t* bitsA = (uint32_t*)(ws);             // 1,179,648 B
    uint32_t* bitsB = (uint32_t*)(ws + 1179648);   // 1,179,648 B
    unsigned* meta  = (unsigned*)(ws + 2359296);   // 32,768 B, zeroed by binarize
    u64* msg        = (u64*)(ws + 2392064);        // 7 boundaries * 2 slots * 73,728 B

    binarize_kernel<<<18432, 256, 0, stream>>>(ma, mb, bitsA, bitsB,
                                               (uint4*)meta);
    pipeline_kernel<<<EWG, PT, 0, stream>>>(sa, sb, bitsA, bitsB, meta, msg);
    expand_kernel<<<18432, 256, 0, stream>>>(bitsA, bitsB, (const int*)meta, out);
}